// Round 2
// baseline (573.376 us; speedup 1.0000x reference)
//
#include <hip/hip_runtime.h>

#define Bsz 512
#define Lsz 512
#define Tsz 128
#define TAG_START 126
#define TAG_STOP 127

__device__ __forceinline__ float rl(float v, int j) {
  return __int_as_float(__builtin_amdgcn_readlane(__float_as_int(v), j));
}
__device__ __forceinline__ float wave_max(float v) {
  #pragma unroll
  for (int off = 32; off > 0; off >>= 1) v = fmaxf(v, __shfl_down(v, off, 64));
  return v;
}
__device__ __forceinline__ float wave_sum(float v) {
  #pragma unroll
  for (int off = 32; off > 0; off >>= 1) v += __shfl_down(v, off, 64);
  return v;
}

// One block per batch element. 128 threads = 2 waves.
// Wave w owns prev-half [w*64, w*64+63]; u[prev] lives in that wave's lanes
// (lane j of wave w holds u[w*64+j]) and is broadcast via v_readlane (VALU,
// no LDS pipe). Each lane accumulates partial sums for next-rows k and k+64
// over its wave's 64 prev. Partials are exchanged through a tiny
// double-buffered LDS array (2 writes + 4 reads + 1 barrier per step).
//
// Carry trick: never materialize fv in-loop. p[tag] = sum_prev er*u.
//   u_next = p * rcp(p1) * exp(emit)      (exact: = exp(fv - m_next))
//   m     += log(p1)                      (off critical path)
//   fv     = emit + m + log(p)            (once, at t = len-1)
__global__ __launch_bounds__(128, 1) void crf_fwd_kernel(
    const float* __restrict__ feats, const float* __restrict__ trans,
    const int* __restrict__ tags, const int* __restrict__ lens,
    float* __restrict__ diff_out)
{
  __shared__ float p_lds[2][2][Tsz];   // [buf][wave][tag]
  __shared__ float wred[2];
  __shared__ float wred2[2];

  const int b   = blockIdx.x;
  const int tid = threadIdx.x;
  const int w   = tid >> 6;      // wave id = prev-half
  const int k   = tid & 63;      // lane
  const int tau = tid;           // this lane's u-ownership tag (= w*64+k)
  const int len = lens[b];
  const float* fb = feats + (size_t)b * Lsz * Tsz;

  // er0[j] = exp(trans[k][w*64+j]), er1[j] = exp(trans[k+64][w*64+j])
  float er0[64], er1[64];
  {
    const float* r0 = trans + (size_t)k * Tsz + w * 64;
    const float* r1 = trans + (size_t)(k + 64) * Tsz + w * 64;
    #pragma unroll
    for (int j = 0; j < 64; j += 4) {
      float4 a = *(const float4*)(r0 + j);
      float4 c = *(const float4*)(r1 + j);
      er0[j+0] = __expf(a.x); er0[j+1] = __expf(a.y);
      er0[j+2] = __expf(a.z); er0[j+3] = __expf(a.w);
      er1[j+0] = __expf(c.x); er1[j+1] = __expf(c.y);
      er1[j+2] = __expf(c.z); er1[j+3] = __expf(c.w);
    }
  }

  // u_0 = exp(fv_init - 0): 1 at START, exp(-10000)->0 elsewhere
  float u  = (tau == TAG_START) ? 1.0f : 0.0f;
  float m  = 0.0f;
  float fv = 0.0f;
  float e0 = fb[tau];                                   // emit_t, t=0
  float e1 = (len > 1) ? fb[Tsz + tau] : 0.0f;          // prefetch t=1
  int buf = 0;

  for (int t = 0; t < len; ++t) {
    // prefetch emit for t+2 (hidden under the FMA phase)
    int tn = t + 2; tn = (tn < len) ? tn : (len - 1);
    float e2 = fb[(size_t)tn * Tsz + tau];
    float ee = __expf(e0);                              // exp(emit_t), off-path

    // matvec partials: rows k, k+64 over prev = w*64 + [0,64)
    float a0 = 0.f, a1 = 0.f, c0 = 0.f, c1 = 0.f;
    #pragma unroll
    for (int j = 0; j < 64; j += 2) {
      float s0 = rl(u, j);
      float s1 = rl(u, j + 1);
      a0 = fmaf(er0[j],     s0, a0);
      a1 = fmaf(er1[j],     s0, a1);
      c0 = fmaf(er0[j + 1], s1, c0);
      c1 = fmaf(er1[j + 1], s1, c1);
    }
    p_lds[buf][w][k]      = a0 + c0;
    p_lds[buf][w][k + 64] = a1 + c1;
    __syncthreads();

    float pa  = p_lds[buf][0][tau];
    float pb  = p_lds[buf][1][tau];
    float q1a = p_lds[buf][0][1];    // tag 1: shift proxy (always finite >0)
    float q1b = p_lds[buf][1][1];
    float p   = pa + pb;
    float p1  = q1a + q1b;

    if (t == len - 1) fv = e0 + m + __logf(p);
    u = p * __builtin_amdgcn_rcpf(p1) * ee;   // exp(fv - m_next), exact
    m += __logf(p1);                          // off critical path
    e0 = e1; e1 = e2;
    buf ^= 1;
  }

  // terminal: logsumexp over tags of fv + trans[START, tag]
  float x = fv + trans[TAG_START * Tsz + tau];   // -inf for START row: ok
  float wm = wave_max(x);
  if (k == 0) wred[w] = wm;
  __syncthreads();
  float mx = fmaxf(wred[0], wred[1]);
  __syncthreads();
  float se = wave_sum(__expf(x - mx));
  if (k == 0) wred[w] = se;
  __syncthreads();
  float fwd_score = mx + __logf(wred[0] + wred[1]);

  // ---- gold score (fused; trivial vs the 512-step chain) ----
  const int* tg = tags + (size_t)b * Lsz;
  float acc = 0.0f;
  for (int pos = tid; pos <= len; pos += 128) {
    int st = (pos == 0)   ? TAG_START : tg[pos - 1];
    int et = (pos == len) ? TAG_STOP  : tg[pos];
    acc += trans[et * Tsz + st];
  }
  for (int l = tid; l < len; l += 128)
    acc += fb[(size_t)l * Tsz + tg[l]];

  float gs = wave_sum(acc);
  if (k == 0) wred2[w] = gs;
  __syncthreads();
  if (tid == 0) diff_out[b] = fwd_score - (wred2[0] + wred2[1]);
}

// loss = mean(diff)
__global__ __launch_bounds__(Bsz) void crf_final_kernel(
    const float* __restrict__ diff, float* __restrict__ out)
{
  int tid = threadIdx.x;
  float v = diff[tid];
  __shared__ float wred[8];
  float s = wave_sum(v);
  int wave = tid >> 6, lane = tid & 63;
  if (lane == 0) wred[wave] = s;
  __syncthreads();
  if (tid == 0) {
    float t = 0.f;
    #pragma unroll
    for (int i = 0; i < 8; ++i) t += wred[i];
    out[0] = t * (1.0f / Bsz);
  }
}

extern "C" void kernel_launch(void* const* d_in, const int* in_sizes, int n_in,
                              void* d_out, int out_size, void* d_ws, size_t ws_size,
                              hipStream_t stream) {
  const float* feats = (const float*)d_in[0];
  const float* trans = (const float*)d_in[1];
  const int*   tags  = (const int*)d_in[2];
  const int*   lens  = (const int*)d_in[3];
  float* out  = (float*)d_out;
  float* diff = (float*)d_ws;

  crf_fwd_kernel<<<Bsz, 128, 0, stream>>>(feats, trans, tags, lens, diff);
  crf_final_kernel<<<1, Bsz, 0, stream>>>(diff, out);
}

// Round 3
// 465.720 us; speedup vs baseline: 1.2312x; 1.2312x over previous
//
#include <hip/hip_runtime.h>

#define Bsz 512
#define Lsz 512
#define Tsz 128
#define TAG_START 126
#define TAG_STOP 127

__device__ __forceinline__ float rl(float v, int j) {
  return __int_as_float(__builtin_amdgcn_readlane(__float_as_int(v), j));
}
__device__ __forceinline__ float wave_max(float v) {
  #pragma unroll
  for (int off = 32; off > 0; off >>= 1) v = fmaxf(v, __shfl_down(v, off, 64));
  return v;
}
__device__ __forceinline__ float wave_sum(float v) {
  #pragma unroll
  for (int off = 32; off > 0; off >>= 1) v += __shfl_down(v, off, 64);
  return v;
}

// Workgroup barrier that drains ONLY LDS ops (lgkmcnt), not global loads
// (vmcnt). __syncthreads() would emit s_waitcnt vmcnt(0) and put the emit
// prefetch's HBM latency (~900 cyc) on the serial chain every step.
__device__ __forceinline__ void lds_barrier() {
  asm volatile("s_waitcnt lgkmcnt(0)\n\ts_barrier" ::: "memory");
}

// One block per batch element, 256 threads = 4 waves.
// Wave w owns prev-quarter [32w, 32w+32): lane j (j<32) holds u[32w+j].
// Each lane computes rows k and k+64 over its wave's 32 prevs:
//   32 readlane + 64 FMA per step (VALU-private, no LDS pipe).
// Partials exchanged via LDS [wave][tag] (stride-1 writes, conflict-free);
// one no-drain barrier per step.
//
// Carry: u = exp(fv - m) maintained directly:
//   u_next = p * rcp(p1) * exp(emit),  m += log(p1)   (p1 = p[tag 1])
//   fv materialized once at t = len-1.
__global__ __launch_bounds__(256, 1) void crf_fwd_kernel(
    const float* __restrict__ feats, const float* __restrict__ trans,
    const int* __restrict__ tags, const int* __restrict__ lens,
    float* __restrict__ diff_out)
{
  __shared__ float p_part[2][4][Tsz];   // [buf][wave][tag]
  __shared__ float wredA[4];
  __shared__ float wredB[4];

  const int b   = blockIdx.x;
  const int tid = threadIdx.x;
  const int w   = tid >> 6;          // wave id = prev-quarter
  const int k   = tid & 63;          // lane
  const int tagu = w * 32 + (k & 31); // tag whose u this lane owns (k<32 only)
  const int len = lens[b];
  const float* fb = feats + (size_t)b * Lsz * Tsz;

  // er0[j] = exp(trans[k][32w+j]), er1[j] = exp(trans[k+64][32w+j])
  float er0[32], er1[32];
  {
    const float* r0 = trans + (size_t)k * Tsz + w * 32;
    const float* r1 = trans + (size_t)(k + 64) * Tsz + w * 32;
    #pragma unroll
    for (int j = 0; j < 32; j += 4) {
      float4 a = *(const float4*)(r0 + j);
      float4 c = *(const float4*)(r1 + j);
      er0[j+0] = __expf(a.x); er0[j+1] = __expf(a.y);
      er0[j+2] = __expf(a.z); er0[j+3] = __expf(a.w);
      er1[j+0] = __expf(c.x); er1[j+1] = __expf(c.y);
      er1[j+2] = __expf(c.z); er1[j+3] = __expf(c.w);
    }
  }

  // u_0 = exp(fv_init): 1 at START, 0 elsewhere (exp(-10000) -> 0 in fp32)
  float u  = (k < 32 && tagu == TAG_START) ? 1.0f : 0.0f;
  float m  = 0.0f;
  float fv = 0.0f;

  // 3-deep emit prefetch (stays in flight across no-drain barriers)
  int t1 = (1 < len) ? 1 : len - 1;
  int t2 = (2 < len) ? 2 : len - 1;
  float e0 = fb[tagu];
  float e1 = fb[(size_t)t1 * Tsz + tagu];
  float e2 = fb[(size_t)t2 * Tsz + tagu];
  int buf = 0;

  for (int t = 0; t < len; ++t) {
    int tn = t + 3; tn = (tn < len) ? tn : (len - 1);
    float e3 = fb[(size_t)tn * Tsz + tagu];   // prefetch t+3
    float ee = __expf(e0);                    // exp(emit_t), off-path

    // matvec partials: rows k and k+64 over prev = 32w + [0,32)
    float a0 = 0.f, a1 = 0.f;
    #pragma unroll
    for (int j = 0; j < 32; ++j) {
      float s = rl(u, j);
      a0 = fmaf(er0[j], s, a0);
      a1 = fmaf(er1[j], s, a1);
    }
    p_part[buf][w][k]      = a0;
    p_part[buf][w][k + 64] = a1;
    lds_barrier();

    float p  = (p_part[buf][0][tagu] + p_part[buf][1][tagu])
             + (p_part[buf][2][tagu] + p_part[buf][3][tagu]);
    float p1 = (p_part[buf][0][1] + p_part[buf][1][1])
             + (p_part[buf][2][1] + p_part[buf][3][1]);   // wave-uniform bcast

    if (t == len - 1) fv = e0 + m + __logf(p);
    u = p * __builtin_amdgcn_rcpf(p1) * ee;   // exp(fv_{t+1} - m_{t+1}), exact
    m += __logf(p1);                          // off critical path
    e0 = e1; e1 = e2; e2 = e3;
    buf ^= 1;
  }

  // terminal: logsumexp over tags of fv + trans[START, tag]
  float x = (k < 32) ? (fv + trans[TAG_START * Tsz + tagu]) : -1e30f;
  float wm = wave_max(x);
  if (k == 0) wredA[w] = wm;
  __syncthreads();
  float mx = fmaxf(fmaxf(wredA[0], wredA[1]), fmaxf(wredA[2], wredA[3]));
  __syncthreads();
  float se = wave_sum((k < 32) ? __expf(x - mx) : 0.0f);
  if (k == 0) wredA[w] = se;
  __syncthreads();
  float fwd_score = mx + __logf((wredA[0] + wredA[1]) + (wredA[2] + wredA[3]));

  // ---- gold score (fused) ----
  const int* tg = tags + (size_t)b * Lsz;
  float acc = 0.0f;
  for (int pos = tid; pos <= len; pos += 256) {
    int st = (pos == 0)   ? TAG_START : tg[pos - 1];
    int et = (pos == len) ? TAG_STOP  : tg[pos];
    acc += trans[et * Tsz + st];
  }
  for (int l = tid; l < len; l += 256)
    acc += fb[(size_t)l * Tsz + tg[l]];

  float gs = wave_sum(acc);
  if (k == 0) wredB[w] = gs;
  __syncthreads();
  if (tid == 0)
    diff_out[b] = fwd_score - ((wredB[0] + wredB[1]) + (wredB[2] + wredB[3]));
}

// loss = mean(diff)
__global__ __launch_bounds__(Bsz) void crf_final_kernel(
    const float* __restrict__ diff, float* __restrict__ out)
{
  int tid = threadIdx.x;
  float v = diff[tid];
  __shared__ float wred[8];
  float s = wave_sum(v);
  int wave = tid >> 6, lane = tid & 63;
  if (lane == 0) wred[wave] = s;
  __syncthreads();
  if (tid == 0) {
    float t = 0.f;
    #pragma unroll
    for (int i = 0; i < 8; ++i) t += wred[i];
    out[0] = t * (1.0f / Bsz);
  }
}

extern "C" void kernel_launch(void* const* d_in, const int* in_sizes, int n_in,
                              void* d_out, int out_size, void* d_ws, size_t ws_size,
                              hipStream_t stream) {
  const float* feats = (const float*)d_in[0];
  const float* trans = (const float*)d_in[1];
  const int*   tags  = (const int*)d_in[2];
  const int*   lens  = (const int*)d_in[3];
  float* out  = (float*)d_out;
  float* diff = (float*)d_ws;

  crf_fwd_kernel<<<Bsz, 256, 0, stream>>>(feats, trans, tags, lens, diff);
  crf_final_kernel<<<1, Bsz, 0, stream>>>(diff, out);
}